// Round 12
// baseline (219.448 us; speedup 1.0000x reference)
//
#include <hip/hip_runtime.h>
#include <hip/hip_bf16.h>

typedef __attribute__((ext_vector_type(8))) short bf16x8;
typedef __attribute__((ext_vector_type(16))) float f32x16;
typedef __attribute__((ext_vector_type(2))) unsigned u32x2;

// packed f32x2 -> bf16x2 (RNE)
__device__ __forceinline__ unsigned pk2(float a, float b) {
    union { __hip_bfloat162 h2; unsigned u; } c;
    c.h2 = __float22bfloat162_rn(make_float2(a, b));
    return c.u;
}

// exact transcription of the reference _hilbert_index_to_xy; returns p = x*d + y
__device__ inline int hilbert_p(int index, int d) {
    int x = 0, y = 0;
    for (int s = 1; s < d; s <<= 1) {
        int rx = (index >> 1) & 1;
        int ry = (index ^ rx) & 1;
        if (ry == 0) {
            if (rx == 1) {
                int nx = s - 1 - y;
                int ny = s - 1 - x;
                x = nx; y = ny;
            }
            int t = x; x = y; y = t;
        }
        x += s * rx;
        y += s * ry;
        index >>= 2;
    }
    return x * d + y;
}

// ---- tile geometry decode (tile index 0..1119) ----
struct TileGeo { int g, h, segrow, dgrid, kt; };
__device__ __forceinline__ TileGeo tile_decode(int b) {
    TileGeo t;
    int g, rb;
    if (b < 640)      { g = 0; rb = b; }
    else if (b < 960) { g = 1; rb = b - 640; }
    else              { g = 2; rb = b - 960; }
    const int nseg = 4 >> g;
    const int hl   = rb / (nseg * 32);
    const int r2   = rb - hl * (nseg * 32);
    t.g      = g;
    t.h      = g * 5 + hl;
    t.kt     = r2 & 31;
    t.segrow = (r2 >> 5) * (2048 << g);
    t.dgrid  = (g == 2) ? 128 : 64;
    return t;
}

// ---- gather (~8 us total, pinned by R8's fusion experiment — not the
// bottleneck). Chunk-linear layouts (R6+, unchanged):
//   kchunk(j,c8)  = ((j>>5)*4 + (c8>>1))*64 + (c8&1)*32 + (j&31)
//   vchunk(dd,k8) = ((k8>>1)*2 + (dd>>5))*64 + (k8&1)*32 + (dd&31)
__device__ __forceinline__ void k_item(int i, const float* __restrict__ K,
                                       short* __restrict__ Kp) {
    const int tile = i >> 9, idx = i & 511;
    const int j = idx >> 3, c8 = idx & 7;
    const TileGeo t = tile_decode(tile);
    const int ii = t.kt * 64 + j;
    const int p  = (t.g == 0) ? ii : hilbert_p(ii << t.g, t.dgrid);
    const float* kp = K + ((size_t)((t.segrow + p) * 16 + t.h)) * 64 + c8 * 8;
    float4 k0 = ((const float4*)kp)[0];
    float4 k1 = ((const float4*)kp)[1];
    union { unsigned u4[4]; bf16x8 v; } ck;
    ck.u4[0] = pk2(k0.x, k0.y); ck.u4[1] = pk2(k0.z, k0.w);
    ck.u4[2] = pk2(k1.x, k1.y); ck.u4[3] = pk2(k1.z, k1.w);
    const int kchunk = ((j >> 5) * 4 + (c8 >> 1)) * 64 + (c8 & 1) * 32 + (j & 31);
    *(bf16x8*)&Kp[(size_t)tile * 4096 + kchunk * 8] = ck.v;
}

__device__ __forceinline__ void v_item(int i, const float* __restrict__ V,
                                       short* __restrict__ Vp) {
    const int tile = i >> 9, idx = i & 511;
    const int k8 = idx >> 6, dd = idx & 63;
    const TileGeo t = tile_decode(tile);
    float rv[8];
#pragma unroll
    for (int u = 0; u < 8; ++u) {
        const int ii = t.kt * 64 + k8 * 8 + u;
        const int p  = (t.g == 0) ? ii : hilbert_p(ii << t.g, t.dgrid);
        rv[u] = V[((size_t)((t.segrow + p) * 16 + t.h)) * 64 + dd];
    }
    union { unsigned u4[4]; bf16x8 v; } o;
    o.u4[0] = pk2(rv[0], rv[1]); o.u4[1] = pk2(rv[2], rv[3]);
    o.u4[2] = pk2(rv[4], rv[5]); o.u4[3] = pk2(rv[6], rv[7]);
    const int vchunk = ((k8 >> 1) * 2 + (dd >> 5)) * 64 + (k8 & 1) * 32 + (dd & 31);
    *(bf16x8*)&Vp[(size_t)tile * 4096 + vchunk * 8] = o.v;
}

__global__ __launch_bounds__(256, 4) void gather_kv(
    const float* __restrict__ K, const float* __restrict__ V,
    short* __restrict__ Kp, short* __restrict__ Vp)
{
    const int gt   = blockIdx.x * 256 + threadIdx.x;
    const int step = gridDim.x * 256;
    for (int i = gt; i < 1120 * 512; i += step) k_item(i, K, Kp);
    for (int i = gt; i < 1120 * 512; i += step) v_item(i, V, Vp);
}

// R12: NO LDS, NO BARRIERS — register-resident K/V, software-pipelined
// direct loads. R0-R11 evidence: every per-pipe lever is flat; the wall is
// the per-tile s_barrier phase-locking all waves into the same phase, so
// MFMA/VALU/LDS burst in lockstep and their times ADD (26%+40%+~30% = the
// whole wall). Fix: delete the coupling.
//  - kf[8]/vf[8] (32+32 VGPR) hold the current tile; next tile's kf loads
//    issue right after S-phase (kf dead), vf loads after PV — each covered
//    by a full compute phase; compiler inserts counted vmcnt before use.
//    (R4 failed because these loads were latency-exposed at use, unpipelined.)
//  - chunk-linear tiles -> every load is a coalesced 1KB global_load_dwordx4;
//    4 waves/block walk the same tile sequence, so L1 serves the re-reads.
//  - waves free-run: phases stagger across ~12 waves/CU, pipes overlap
//    across waves instead of serializing within the lockstep.
//  - l back on VALU (R11's l-via-MFMA was neutral; saves 16+ VGPR).
//  - VGPR ~160 targeted via __launch_bounds__(256,3); spill would show as a
//    WRITE_SIZE jump (R2 signature).
__global__ __launch_bounds__(256, 3) void attn_kernel(
    const float* __restrict__ Q, float* __restrict__ O,
    const short* __restrict__ Kp, const short* __restrict__ Vp)
{
    const int bx = blockIdx.x;
    const int g  = bx / 320;
    const int r  = bx - g * 320;
    const int hl = r >> 6;
    const int qb = r & 63;
    const int h  = g * 5 + hl;
    const int qglob = qb * 128;
    const int seg   = qb >> (4 + g);
    const int tile0 = ((g == 0) ? 0 : (g == 1) ? 640 : 960) + (hl * (4 >> g) + seg) * 32;

    const int tid  = threadIdx.x;
    const int wave = tid >> 6;
    const int lane = tid & 63;
    const int l31  = lane & 31;
    const int hi   = lane >> 5;

    // head 15 belongs to no group: zero it here (d_out is poisoned each run).
    if (g == 0 && hl == 0) {
        const float4 z = make_float4(0.f, 0.f, 0.f, 0.f);
        for (int i = tid; i < 2048; i += 256) {
            int row = qglob + (i >> 4);
            ((float4*)O)[(size_t)(row * 16 + 15) * 16 + (i & 15)] = z;
        }
    }

    // ---- Q fragments (B-operand of S^T = K.Q^T, 32x32x16)
    const float cs = 0.125f * 1.44269504088896f;   // scale * log2(e)
    bf16x8 qf[4];
    {
        const int qrow = qglob + wave * 32 + l31;
        const float* qp = Q + ((size_t)(qrow * 16 + h)) * 64;
#pragma unroll
        for (int ks = 0; ks < 4; ++ks) {
            const float4* p4 = (const float4*)(qp + ks * 16 + hi * 8);
            float4 a = p4[0], b = p4[1];
            union { unsigned u[4]; bf16x8 v; } f;
            f.u[0] = pk2(a.x * cs, a.y * cs); f.u[1] = pk2(a.z * cs, a.w * cs);
            f.u[2] = pk2(b.x * cs, b.y * cs); f.u[3] = pk2(b.z * cs, b.w * cs);
            qf[ks] = f.v;
        }
    }

    f32x16 z16;
#pragma unroll
    for (int rr = 0; rr < 16; ++rr) z16[rr] = 0.f;

    f32x16 oacc[2];
    oacc[0] = z16; oacc[1] = z16;
    float lp = 0.f;

    // per-lane fragment base within a tile (shorts): lane*8 shorts = 16 B
    const short* kp0 = Kp + ((size_t)tile0 << 12) + lane * 8;
    const short* vp0 = Vp + ((size_t)tile0 << 12) + lane * 8;

    // ---- register-resident current tile (32 + 32 VGPR)
    bf16x8 kf[8], vf[8];
#pragma unroll
    for (int i = 0; i < 8; ++i) kf[i] = *(const bf16x8*)&kp0[i * 512];
#pragma unroll
    for (int i = 0; i < 8; ++i) vf[i] = *(const bf16x8*)&vp0[i * 512];

    for (int kt = 0; kt < 32; ++kt) {
        const short* kp_n = kp0 + (size_t)(kt + 1) * 4096;
        const short* vp_n = vp0 + (size_t)(kt + 1) * 4096;

        // ---- S-phase: S^T = K.Q^T, exp2, pack.
        // m(reg,hi) = (reg&3) + 8*(reg>>2) + 4*hi
        float lacc = 0.f;
        unsigned dw[16];   // dw[ks*4 + j*2 + hT]
        __builtin_amdgcn_s_setprio(1);
#pragma unroll
        for (int kb = 0; kb < 2; ++kb) {
            f32x16 sa;
            sa = __builtin_amdgcn_mfma_f32_32x32x16_bf16(kf[kb * 4 + 0], qf[0], z16, 0, 0, 0);
            sa = __builtin_amdgcn_mfma_f32_32x32x16_bf16(kf[kb * 4 + 1], qf[1], sa, 0, 0, 0);
            sa = __builtin_amdgcn_mfma_f32_32x32x16_bf16(kf[kb * 4 + 2], qf[2], sa, 0, 0, 0);
            sa = __builtin_amdgcn_mfma_f32_32x32x16_bf16(kf[kb * 4 + 3], qf[3], sa, 0, 0, 0);
            float pe[16];
#pragma unroll
            for (int rr = 0; rr < 16; ++rr) pe[rr] = __builtin_amdgcn_exp2f(sa[rr]);
            lacc += (((pe[0] + pe[1]) + (pe[2] + pe[3])) + ((pe[4] + pe[5]) + (pe[6] + pe[7])))
                  + (((pe[8] + pe[9]) + (pe[10] + pe[11])) + ((pe[12] + pe[13]) + (pe[14] + pe[15])));
#pragma unroll
            for (int kslo = 0; kslo < 2; ++kslo)
#pragma unroll
                for (int j = 0; j < 2; ++j)
#pragma unroll
                    for (int hT = 0; hT < 2; ++hT) {
                        const int r0 = 2 * j + 8 * kslo + 4 * hT;
                        dw[(kb * 2 + kslo) * 4 + j * 2 + hT] = pk2(pe[r0], pe[r0 + 1]);
                    }
        }
        __builtin_amdgcn_s_setprio(0);
        lp += lacc;

        // ---- kf dead: issue next tile's K loads NOW (covered by the rest
        // of this iteration's compute; compiler waits before next S-phase).
        __builtin_amdgcn_sched_barrier(0);
        if (kt < 31) {
#pragma unroll
            for (int i = 0; i < 8; ++i) kf[i] = *(const bf16x8*)&kp_n[i * 512];
        }
        __builtin_amdgcn_sched_barrier(0);

        // ---- assemble PV A-frags via permlane32_swap
        bf16x8 pa[4];
#pragma unroll
        for (int ks = 0; ks < 4; ++ks) {
            u32x2 r0 = __builtin_amdgcn_permlane32_swap(dw[ks * 4 + 0], dw[ks * 4 + 1], false, false);
            u32x2 r1 = __builtin_amdgcn_permlane32_swap(dw[ks * 4 + 2], dw[ks * 4 + 3], false, false);
            union { unsigned u[4]; bf16x8 v; } p;
            p.u[0] = r0[0]; p.u[1] = r1[0]; p.u[2] = r0[1]; p.u[3] = r1[1];
            pa[ks] = p.v;
        }

        // ---- PV: O += P.V (vf loaded one full iteration ago; compiler
        // inserts the counted wait here)
        __builtin_amdgcn_s_setprio(1);
#pragma unroll
        for (int ks = 0; ks < 4; ++ks) {
            oacc[0] = __builtin_amdgcn_mfma_f32_32x32x16_bf16(pa[ks], vf[ks * 2 + 0], oacc[0], 0, 0, 0);
            oacc[1] = __builtin_amdgcn_mfma_f32_32x32x16_bf16(pa[ks], vf[ks * 2 + 1], oacc[1], 0, 0, 0);
        }
        __builtin_amdgcn_s_setprio(0);

        // ---- vf dead: issue next tile's V loads (covered by next S-phase)
        __builtin_amdgcn_sched_barrier(0);
        if (kt < 31) {
#pragma unroll
            for (int i = 0; i < 8; ++i) vf[i] = *(const bf16x8*)&vp_n[i * 512];
        }
        __builtin_amdgcn_sched_barrier(0);
    }

    // ---- l: lane pair (l31, hi=0/1) each hold half the key-sum for q=l31
    float ltot = lp + __shfl_xor(lp, 32, 64);
    float linv = 1.0f / ltot;

    // ---- epilogue: O / l. row = q = (rr&3)+8*(rr>>2)+4*hi, col = l31/32+l31
#pragma unroll
    for (int rr = 0; rr < 16; ++rr) {
        const int m = (rr & 3) + ((rr >> 2) << 3) + (hi << 2);
        float inv = __shfl(linv, m, 64);   // linv for q=m lives at lane m
        const int qrow = qglob + wave * 32 + m;
        float* op = O + ((size_t)(qrow * 16 + h)) * 64 + l31;
        op[0]  = oacc[0][rr] * inv;
        op[32] = oacc[1][rr] * inv;
    }
}

extern "C" void kernel_launch(void* const* d_in, const int* in_sizes, int n_in,
                              void* d_out, int out_size, void* d_ws, size_t ws_size,
                              hipStream_t stream) {
    const float* q = (const float*)d_in[0];
    const float* k = (const float*)d_in[1];
    const float* v = (const float*)d_in[2];
    float* out = (float*)d_out;
    short* Kp = (short*)d_ws;                       // 1120 tiles * 8 KB = 9.18 MB
    short* Vp = Kp + (size_t)1120 * 4096;           // + 9.18 MB  (ws total ~18.4 MB)

    gather_kv<<<960, 256, 0, stream>>>(k, v, Kp, Vp);
    attn_kernel<<<960, 256, 0, stream>>>(q, out, Kp, Vp);
}